// Round 1
// baseline (543.709 us; speedup 1.0000x reference)
//
#include <hip/hip_runtime.h>
#include <math.h>

#define TN 768   // T = N*M flattened nodes
#define HD 64    // hidden H
#define FF 32    // feature dim
#define OUTD 64  // invariant out
#define LL 2     // layers

__device__ __forceinline__ float silu_f(float x) {
    return x / (1.0f + __expf(-x));
}

// ---------------- K0: embedding + x_vec init ----------------
__global__ void k_embed(const float* __restrict__ pos, const float* __restrict__ feat,
                        const float* __restrict__ w_emb, const float* __restrict__ b_emb,
                        float* __restrict__ h, float* __restrict__ x_vec) {
    int t = blockIdx.x;
    int j = threadIdx.x;  // 64
    __shared__ float sf[FF];
    if (j < FF) sf[j] = feat[t * FF + j];
    __syncthreads();
    float acc = b_emb[j];
#pragma unroll
    for (int f = 0; f < FF; ++f) acc += sf[f] * w_emb[f * HD + j];
    h[t * HD + j] = acc;
    if (j < 6) {
        // x_vec[t][k][d] = x[t][d], k = j/3, d = j%3
        x_vec[t * 6 + j] = pos[t * 3 + (j % 3)];
    }
}

// ---------------- K1: per-node A = h@we1[:H]+be1, Bv = h@we1[H:2H] ----------------
__global__ void k_node_pre(const float* __restrict__ h, const float* __restrict__ we1,
                           const float* __restrict__ be1, int l,
                           float* __restrict__ A, float* __restrict__ Bv) {
    int t = blockIdx.x;
    int tid = threadIdx.x;  // 128
    __shared__ float sh[HD];
    if (tid < HD) sh[tid] = h[t * HD + tid];
    __syncthreads();
    int j = tid & 63;
    const float* w = we1 + (size_t)l * 130 * HD;
    if (tid < 64) {
        float acc = be1[l * HD + j];
#pragma unroll
        for (int i = 0; i < HD; ++i) acc += sh[i] * w[i * HD + j];
        A[t * HD + j] = acc;
    } else {
        float acc = 0.f;
#pragma unroll
        for (int i = 0; i < HD; ++i) acc += sh[i] * w[(HD + i) * HD + j];
        Bv[t * HD + j] = acc;
    }
}

// ---------------- K2: edge kernel, one block per receiver ----------------
__global__ __launch_bounds__(256) void k_edge(
    const float* __restrict__ x_vec, const float* __restrict__ A,
    const float* __restrict__ Bv, const float* __restrict__ we1,
    const float* __restrict__ we2, const float* __restrict__ be2,
    const float* __restrict__ wx1, const float* __restrict__ bx1,
    const float* __restrict__ wx2, int l,
    float* __restrict__ agg, float* __restrict__ x_upd)
{
    const int r = blockIdx.x;
    const int tid = threadIdx.x;
    const int tj = tid & 15;   // output-col tile; consecutive lanes -> shuffle reduce
    const int ti = tid >> 4;   // output-row tile

    __shared__ __align__(16) float sWe2[HD][HD];
    __shared__ __align__(16) float sWx1[HD][HD];
    __shared__ __align__(16) float sM1T[HD][HD + 4];  // [k][i], padded
    __shared__ __align__(16) float sM2T[HD][HD + 4];
    __shared__ float sEdge[HD][8];                    // diff[6], inv[2]
    __shared__ float sBvr[HD];
    __shared__ float sC0[HD], sC1[HD], sBe2v[HD], sBx1v[HD];
    __shared__ float sWx2v[HD][2];

    // preload weights for this layer
    const float* w2 = we2 + (size_t)l * HD * HD;
    const float* w3 = wx1 + (size_t)l * HD * HD;
    for (int idx = tid; idx < HD * HD / 4; idx += 256) {
        ((float4*)&sWe2[0][0])[idx] = ((const float4*)w2)[idx];
        ((float4*)&sWx1[0][0])[idx] = ((const float4*)w3)[idx];
    }
    if (tid < HD) {
        sBvr[tid]  = Bv[r * HD + tid];
        sC0[tid]   = we1[((size_t)l * 130 + 128) * HD + tid];
        sC1[tid]   = we1[((size_t)l * 130 + 129) * HD + tid];
        sBe2v[tid] = be2[l * HD + tid];
        sBx1v[tid] = bx1[l * HD + tid];
        sWx2v[tid][0] = wx2[((size_t)l * HD + tid) * 2 + 0];
        sWx2v[tid][1] = wx2[((size_t)l * HD + tid) * 2 + 1];
    }
    float xr[6];
#pragma unroll
    for (int c = 0; c < 6; ++c) xr[c] = x_vec[r * 6 + c];
    __syncthreads();

    float aggP[4] = {0.f, 0.f, 0.f, 0.f};
    float accX[6] = {0.f, 0.f, 0.f, 0.f, 0.f, 0.f};

#pragma unroll 1
    for (int s0 = 0; s0 < TN; s0 += 64) {
        // ---- phase A: sqnorm/diff + build M1T (transposed) ----
        float sq[4][2];
#pragma unroll
        for (int ic = 0; ic < 4; ++ic) {
            int i = 4 * ti + ic;
            int s = s0 + i;
            float d0 = x_vec[s * 6 + 0] - xr[0];
            float d1 = x_vec[s * 6 + 1] - xr[1];
            float d2 = x_vec[s * 6 + 2] - xr[2];
            float d3 = x_vec[s * 6 + 3] - xr[3];
            float d4 = x_vec[s * 6 + 4] - xr[4];
            float d5 = x_vec[s * 6 + 5] - xr[5];
            float q0 = d0 * d0 + d1 * d1 + d2 * d2;
            float q1 = d3 * d3 + d4 * d4 + d5 * d5;
            sq[ic][0] = q0; sq[ic][1] = q1;
            if (tj == 0) {
                sEdge[i][0] = d0; sEdge[i][1] = d1; sEdge[i][2] = d2;
                sEdge[i][3] = d3; sEdge[i][4] = d4; sEdge[i][5] = d5;
                sEdge[i][6] = 1.f / (sqrtf(q0 + 1e-8f) + 1.f);
                sEdge[i][7] = 1.f / (sqrtf(q1 + 1e-8f) + 1.f);
            }
        }
        {
            float m1v[4][4];  // [ic][jc]
#pragma unroll
            for (int ic = 0; ic < 4; ++ic) {
                int s = s0 + 4 * ti + ic;
                const float4 a = *(const float4*)&A[s * HD + 4 * tj];
                float av[4] = {a.x, a.y, a.z, a.w};
#pragma unroll
                for (int jc = 0; jc < 4; ++jc) {
                    int j = 4 * tj + jc;
                    float pre = av[jc] + sBvr[j] + sq[ic][0] * sC0[j] + sq[ic][1] * sC1[j];
                    m1v[ic][jc] = silu_f(pre);
                }
            }
#pragma unroll
            for (int jc = 0; jc < 4; ++jc) {
                *(float4*)&sM1T[4 * tj + jc][4 * ti] =
                    make_float4(m1v[0][jc], m1v[1][jc], m1v[2][jc], m1v[3][jc]);
            }
        }
        __syncthreads();

        // ---- phase B: M2 = silu(M1 @ we2 + be2), write M2T, accumulate agg ----
        {
            float acc[4][4] = {};
#pragma unroll 16
            for (int k = 0; k < HD; ++k) {
                float4 a = *(const float4*)&sM1T[k][4 * ti];
                float4 b = *(const float4*)&sWe2[k][4 * tj];
                float av[4] = {a.x, a.y, a.z, a.w};
                float bv[4] = {b.x, b.y, b.z, b.w};
#pragma unroll
                for (int ic = 0; ic < 4; ++ic)
#pragma unroll
                    for (int jc = 0; jc < 4; ++jc)
                        acc[ic][jc] += av[ic] * bv[jc];
            }
            int rl = r - s0;  // masked local row if in [0,64)
#pragma unroll
            for (int ic = 0; ic < 4; ++ic) {
                int i = 4 * ti + ic;
                bool masked = (i == rl);
#pragma unroll
                for (int jc = 0; jc < 4; ++jc) {
                    float v = silu_f(acc[ic][jc] + sBe2v[4 * tj + jc]);
                    if (masked) v = 0.f;
                    acc[ic][jc] = v;
                    aggP[jc] += v;
                }
            }
#pragma unroll
            for (int jc = 0; jc < 4; ++jc) {
                *(float4*)&sM2T[4 * tj + jc][4 * ti] =
                    make_float4(acc[0][jc], acc[1][jc], acc[2][jc], acc[3][jc]);
            }
        }
        __syncthreads();

        // ---- phase C: P = silu(M2 @ wx1 + bx1); phi = P @ wx2; accumulate x_upd ----
        {
            float acc[4][4] = {};
#pragma unroll 16
            for (int k = 0; k < HD; ++k) {
                float4 a = *(const float4*)&sM2T[k][4 * ti];
                float4 b = *(const float4*)&sWx1[k][4 * tj];
                float av[4] = {a.x, a.y, a.z, a.w};
                float bv[4] = {b.x, b.y, b.z, b.w};
#pragma unroll
                for (int ic = 0; ic < 4; ++ic)
#pragma unroll
                    for (int jc = 0; jc < 4; ++jc)
                        acc[ic][jc] += av[ic] * bv[jc];
            }
            float phiP[4][2] = {};
#pragma unroll
            for (int ic = 0; ic < 4; ++ic) {
#pragma unroll
                for (int jc = 0; jc < 4; ++jc) {
                    int j = 4 * tj + jc;
                    float p = silu_f(acc[ic][jc] + sBx1v[j]);
                    phiP[ic][0] += p * sWx2v[j][0];
                    phiP[ic][1] += p * sWx2v[j][1];
                }
            }
            // butterfly reduce over the 16 tj lanes (consecutive within wave)
#pragma unroll
            for (int m = 1; m < 16; m <<= 1) {
#pragma unroll
                for (int ic = 0; ic < 4; ++ic) {
                    phiP[ic][0] += __shfl_xor(phiP[ic][0], m, 64);
                    phiP[ic][1] += __shfl_xor(phiP[ic][1], m, 64);
                }
            }
            if (tj == 0) {
#pragma unroll
                for (int ic = 0; ic < 4; ++ic) {
                    int i = 4 * ti + ic;
                    float f0 = phiP[ic][0] * sEdge[i][6];
                    float f1 = phiP[ic][1] * sEdge[i][7];
                    accX[0] += f0 * sEdge[i][0];
                    accX[1] += f0 * sEdge[i][1];
                    accX[2] += f0 * sEdge[i][2];
                    accX[3] += f1 * sEdge[i][3];
                    accX[4] += f1 * sEdge[i][4];
                    accX[5] += f1 * sEdge[i][5];
                }
            }
        }
        __syncthreads();
    }

    // ---- final reductions (reuse sM1T / sM2T as scratch) ----
    float* sRed = &sM1T[0][0];  // [16][64] partials for agg
    float* sRx  = &sM2T[0][0];  // [16][6] partials for x_upd
#pragma unroll
    for (int jc = 0; jc < 4; ++jc) sRed[ti * 64 + 4 * tj + jc] = aggP[jc];
    if (tj == 0) {
#pragma unroll
        for (int c = 0; c < 6; ++c) sRx[ti * 6 + c] = accX[c];
    }
    __syncthreads();
    if (tid < 64) {
        float s = 0.f;
#pragma unroll
        for (int q = 0; q < 16; ++q) s += sRed[q * 64 + tid];
        agg[r * HD + tid] = s;
    } else if (tid < 70) {
        int c = tid - 64;
        float s = 0.f;
#pragma unroll
        for (int q = 0; q < 16; ++q) s += sRx[q * 6 + c];
        x_upd[r * 6 + c] = s;
    }
}

// ---------------- K3: node update ----------------
__global__ void k_node_upd(float* __restrict__ h, const float* __restrict__ agg,
                           const float* __restrict__ wh1, const float* __restrict__ bh1,
                           const float* __restrict__ wh2, const float* __restrict__ bh2,
                           float* __restrict__ x_vec, const float* __restrict__ x_upd, int l)
{
    int t = blockIdx.x;
    int j = threadIdx.x;  // 64
    __shared__ float sh[HD], sa[HD], su[HD];
    sh[j] = h[t * HD + j];
    sa[j] = agg[t * HD + j];
    __syncthreads();
    const float* w1 = wh1 + (size_t)l * 128 * HD;
    float acc = bh1[l * HD + j];
#pragma unroll
    for (int i = 0; i < HD; ++i) acc += sh[i] * w1[i * HD + j];
#pragma unroll
    for (int i = 0; i < HD; ++i) acc += sa[i] * w1[(HD + i) * HD + j];
    su[j] = silu_f(acc);
    __syncthreads();
    const float* w2 = wh2 + (size_t)l * HD * HD;
    float v = 0.f;
#pragma unroll
    for (int i = 0; i < HD; ++i) v += su[i] * w2[i * HD + j];
    h[t * HD + j] = sh[j] + v + bh2[l * HD + j];
    if (j < 6) x_vec[t * 6 + j] += x_upd[t * 6 + j] * (1.0f / 767.0f);
}

// ---------------- K4: outputs ----------------
__global__ void k_head(const float* __restrict__ h, const float* __restrict__ x_vec,
                       const float* __restrict__ pos, const float* __restrict__ w_head,
                       const float* __restrict__ b_head, float* __restrict__ out)
{
    int t = blockIdx.x;
    int j = threadIdx.x;  // 64
    __shared__ float sh[HD];
    sh[j] = h[t * HD + j];
    __syncthreads();
    float acc = b_head[j];
#pragma unroll
    for (int i = 0; i < HD; ++i) acc += sh[i] * w_head[i * OUTD + j];
    out[TN * 6 + t * OUTD + j] = acc;          // scalars after vectors
    if (j < 6) out[t * 6 + j] = x_vec[t * 6 + j] - pos[t * 3 + (j % 3)];
}

extern "C" void kernel_launch(void* const* d_in, const int* in_sizes, int n_in,
                              void* d_out, int out_size, void* d_ws, size_t ws_size,
                              hipStream_t stream)
{
    const float* pos    = (const float*)d_in[0];
    const float* feat   = (const float*)d_in[1];
    const float* w_emb  = (const float*)d_in[2];
    const float* b_emb  = (const float*)d_in[3];
    const float* we1    = (const float*)d_in[4];
    const float* be1    = (const float*)d_in[5];
    const float* we2    = (const float*)d_in[6];
    const float* be2    = (const float*)d_in[7];
    const float* wx1    = (const float*)d_in[8];
    const float* bx1    = (const float*)d_in[9];
    const float* wx2    = (const float*)d_in[10];
    const float* wh1    = (const float*)d_in[11];
    const float* bh1    = (const float*)d_in[12];
    const float* wh2    = (const float*)d_in[13];
    const float* bh2    = (const float*)d_in[14];
    const float* w_head = (const float*)d_in[15];
    const float* b_head = (const float*)d_in[16];
    float* out = (float*)d_out;

    float* ws    = (float*)d_ws;
    float* h     = ws;                 // TN*HD
    float* x_vec = h + TN * HD;        // TN*6
    float* Abuf  = x_vec + TN * 6;     // TN*HD
    float* Bvbuf = Abuf + TN * HD;     // TN*HD
    float* aggb  = Bvbuf + TN * HD;    // TN*HD
    float* x_upd = aggb + TN * HD;     // TN*6

    k_embed<<<TN, 64, 0, stream>>>(pos, feat, w_emb, b_emb, h, x_vec);
    for (int l = 0; l < LL; ++l) {
        k_node_pre<<<TN, 128, 0, stream>>>(h, we1, be1, l, Abuf, Bvbuf);
        k_edge<<<TN, 256, 0, stream>>>(x_vec, Abuf, Bvbuf, we1, we2, be2,
                                       wx1, bx1, wx2, l, aggb, x_upd);
        k_node_upd<<<TN, 64, 0, stream>>>(h, aggb, wh1, bh1, wh2, bh2, x_vec, x_upd, l);
    }
    k_head<<<TN, 64, 0, stream>>>(h, x_vec, pos, w_head, b_head, out);
}

// Round 2
// 347.513 us; speedup vs baseline: 1.5646x; 1.5646x over previous
//
#include <hip/hip_runtime.h>
#include <math.h>

#define TN 768   // T = N*M flattened nodes
#define HD 64    // hidden H
#define FF 32    // feature dim
#define OUTD 64  // invariant out
#define LL 2     // layers

typedef short short8 __attribute__((ext_vector_type(8)));
typedef float f32x4 __attribute__((ext_vector_type(4)));
typedef unsigned int uint4v __attribute__((ext_vector_type(4)));

__device__ __forceinline__ float silu_f(float x) {
    return x / (1.0f + __expf(-x));
}

// split fp32 x into hi + lo bf16 parts (truncation split; |err| ~ 2^-17 |x|)
__device__ __forceinline__ void bf16_split(float x, short& hi, short& lo) {
    unsigned int u = __float_as_uint(x);
    unsigned int uh = u & 0xFFFF0000u;
    hi = (short)(uh >> 16);
    float r = x - __uint_as_float(uh);
    lo = (short)(__float_as_uint(r) >> 16);
}

// ---------------- K0: embedding + x_vec init ----------------
__global__ void k_embed(const float* __restrict__ pos, const float* __restrict__ feat,
                        const float* __restrict__ w_emb, const float* __restrict__ b_emb,
                        float* __restrict__ h, float* __restrict__ x_vec) {
    int t = blockIdx.x;
    int j = threadIdx.x;  // 64
    __shared__ float sf[FF];
    if (j < FF) sf[j] = feat[t * FF + j];
    __syncthreads();
    float acc = b_emb[j];
#pragma unroll
    for (int f = 0; f < FF; ++f) acc += sf[f] * w_emb[f * HD + j];
    h[t * HD + j] = acc;
    if (j < 6) {
        x_vec[t * 6 + j] = pos[t * 3 + (j % 3)];
    }
}

// ---------------- K1: per-node A = h@we1[:H]+be1, Bv = h@we1[H:2H] ----------------
__global__ void k_node_pre(const float* __restrict__ h, const float* __restrict__ we1,
                           const float* __restrict__ be1, int l,
                           float* __restrict__ A, float* __restrict__ Bv) {
    int t = blockIdx.x;
    int tid = threadIdx.x;  // 128
    __shared__ float sh[HD];
    if (tid < HD) sh[tid] = h[t * HD + tid];
    __syncthreads();
    int j = tid & 63;
    const float* w = we1 + (size_t)l * 130 * HD;
    if (tid < 64) {
        float acc = be1[l * HD + j];
#pragma unroll
        for (int i = 0; i < HD; ++i) acc += sh[i] * w[i * HD + j];
        A[t * HD + j] = acc;
    } else {
        float acc = 0.f;
#pragma unroll
        for (int i = 0; i < HD; ++i) acc += sh[i] * w[(HD + i) * HD + j];
        Bv[t * HD + j] = acc;
    }
}

// ---------------- K2: edge kernel, one block per receiver, MFMA split-bf16 ----------------
// 4 waves/block; wave w owns output rows [16w,16w+16). Lane = (q=lane>>4, m=lane&15).
// GEMM1: M2pre = M1[64x64] @ We2[64x64]; GEMM2: Ppre = M2[64x64] @ Wx1[64x64]
// A-frag (16x16x32): A[m=lane&15][k=q*8+j]; B-frag: B[k=q*8+j][n=lane&15];
// C/D: col=lane&15, row=q*4+reg  (verified layouts, m89/m120)
__global__ __launch_bounds__(256, 2) void k_edge(
    const float* __restrict__ x_vec, const float* __restrict__ A,
    const float* __restrict__ Bv, const float* __restrict__ we1,
    const float* __restrict__ we2, const float* __restrict__ be2,
    const float* __restrict__ wx1, const float* __restrict__ bx1,
    const float* __restrict__ wx2, int l,
    float* __restrict__ agg, float* __restrict__ x_upd)
{
    const int r = blockIdx.x;
    const int tid = threadIdx.x;
    const int wv = tid >> 6;
    const int lane = tid & 63;
    const int q = lane >> 4;
    const int m = lane & 15;

    __shared__ __align__(16) union USm {
        struct { unsigned short W2h[64 * 72], W2l[64 * 72], W3h[64 * 72], W3l[64 * 72]; } st;
        unsigned int sM2[64 * 76];   // packed hi|lo<<16 bf16 of M2, stride 76 (2-way-free banks)
    } u;
    __shared__ __align__(16) float sPhi[64][2];
    __shared__ __align__(16) float sAgg[4][64];
    __shared__ __align__(16) float sXred[64][8];
    __shared__ __align__(16) float sBvr[64];
    __shared__ __align__(16) float sC0[64];
    __shared__ __align__(16) float sC1[64];

    // ---- stage weights into LDS as hi/lo bf16, TRANSPOSED [n][k] for B-frag reads ----
    const float* w2 = we2 + (size_t)l * HD * HD;
    const float* w3 = wx1 + (size_t)l * HD * HD;
    for (int e = tid; e < HD * HD; e += 256) {
        int k = e >> 6, n = e & 63;
        short h16, l16;
        bf16_split(w2[e], h16, l16);
        u.st.W2h[n * 72 + k] = (unsigned short)h16;
        u.st.W2l[n * 72 + k] = (unsigned short)l16;
        bf16_split(w3[e], h16, l16);
        u.st.W3h[n * 72 + k] = (unsigned short)h16;
        u.st.W3l[n * 72 + k] = (unsigned short)l16;
    }
    __syncthreads();

    // ---- load all B-fragments to registers (reused across all 12 batches) ----
    short8 bW2h[4][2], bW2l[4][2], bW3h[4][2], bW3l[4][2];
#pragma unroll
    for (int nt = 0; nt < 4; ++nt)
#pragma unroll
        for (int kt = 0; kt < 2; ++kt) {
            int idx = (nt * 16 + m) * 72 + kt * 32 + 8 * q;
            bW2h[nt][kt] = *(const short8*)&u.st.W2h[idx];
            bW2l[nt][kt] = *(const short8*)&u.st.W2l[idx];
            bW3h[nt][kt] = *(const short8*)&u.st.W3h[idx];
            bW3l[nt][kt] = *(const short8*)&u.st.W3l[idx];
        }
    __syncthreads();  // staging area now dead; sM2 may reuse it

    if (tid < HD) {
        sBvr[tid] = Bv[r * HD + tid];
        sC0[tid] = we1[((size_t)l * 130 + 128) * HD + tid];
        sC1[tid] = we1[((size_t)l * 130 + 129) * HD + tid];
    }
    // per-lane column constants (col = nt*16+m)
    float be2v[4], bx1v[4], w20[4], w21[4];
#pragma unroll
    for (int nt = 0; nt < 4; ++nt) {
        int col = nt * 16 + m;
        be2v[nt] = be2[l * HD + col];
        bx1v[nt] = bx1[l * HD + col];
        w20[nt] = wx2[((size_t)l * HD + col) * 2 + 0];
        w21[nt] = wx2[((size_t)l * HD + col) * 2 + 1];
    }
    float xr[6];
#pragma unroll
    for (int c = 0; c < 6; ++c) xr[c] = x_vec[r * 6 + c];
    __syncthreads();

    float aggP[4] = {0.f, 0.f, 0.f, 0.f};
    float accX[6] = {0.f, 0.f, 0.f, 0.f, 0.f, 0.f};
    float dk[6] = {0.f, 0.f, 0.f, 0.f, 0.f, 0.f};
    float ik0 = 0.f, ik1 = 0.f;

#pragma unroll 1
    for (int s0 = 0; s0 < TN; s0 += 64) {
        // ---- phase A: row sA = s0 + 16*wv + m; build M1 A-frags in registers ----
        const int sA = s0 + 16 * wv + m;
        float d0 = x_vec[sA * 6 + 0] - xr[0];
        float d1 = x_vec[sA * 6 + 1] - xr[1];
        float d2 = x_vec[sA * 6 + 2] - xr[2];
        float d3 = x_vec[sA * 6 + 3] - xr[3];
        float d4 = x_vec[sA * 6 + 4] - xr[4];
        float d5 = x_vec[sA * 6 + 5] - xr[5];
        float q0 = d0 * d0 + d1 * d1 + d2 * d2;
        float q1 = d3 * d3 + d4 * d4 + d5 * d5;
        if (q == 0) {
            dk[0] = d0; dk[1] = d1; dk[2] = d2; dk[3] = d3; dk[4] = d4; dk[5] = d5;
            ik0 = 1.f / (sqrtf(q0 + 1e-8f) + 1.f);
            ik1 = 1.f / (sqrtf(q1 + 1e-8f) + 1.f);
        }
        short8 a1h[2], a1l[2];
#pragma unroll
        for (int kt = 0; kt < 2; ++kt) {
            int jb = kt * 32 + 8 * q;
            float av[8], bb[8], c0[8], c1[8];
            *(float4*)&av[0] = *(const float4*)&A[sA * HD + jb];
            *(float4*)&av[4] = *(const float4*)&A[sA * HD + jb + 4];
            *(float4*)&bb[0] = *(const float4*)&sBvr[jb];
            *(float4*)&bb[4] = *(const float4*)&sBvr[jb + 4];
            *(float4*)&c0[0] = *(const float4*)&sC0[jb];
            *(float4*)&c0[4] = *(const float4*)&sC0[jb + 4];
            *(float4*)&c1[0] = *(const float4*)&sC1[jb];
            *(float4*)&c1[4] = *(const float4*)&sC1[jb + 4];
#pragma unroll
            for (int jj = 0; jj < 8; ++jj) {
                float pre = av[jj] + bb[jj] + q0 * c0[jj] + q1 * c1[jj];
                float mv = silu_f(pre);
                short hh, ll2;
                bf16_split(mv, hh, ll2);
                a1h[kt][jj] = hh;
                a1l[kt][jj] = ll2;
            }
        }

        // ---- phase B: M2pre = M1 @ We2 (3-mfma split), epilogue -> agg partials + sM2 ----
        const int rl = r - s0;  // local self row (if in [0,64))
#pragma unroll
        for (int nt = 0; nt < 4; ++nt) {
            f32x4 acc = {0.f, 0.f, 0.f, 0.f};
#pragma unroll
            for (int kt = 0; kt < 2; ++kt) {
                acc = __builtin_amdgcn_mfma_f32_16x16x32_bf16(a1h[kt], bW2h[nt][kt], acc, 0, 0, 0);
                acc = __builtin_amdgcn_mfma_f32_16x16x32_bf16(a1l[kt], bW2h[nt][kt], acc, 0, 0, 0);
                acc = __builtin_amdgcn_mfma_f32_16x16x32_bf16(a1h[kt], bW2l[nt][kt], acc, 0, 0, 0);
            }
            int col = nt * 16 + m;
#pragma unroll
            for (int reg = 0; reg < 4; ++reg) {
                int il = 16 * wv + 4 * q + reg;
                float v = silu_f(acc[reg] + be2v[nt]);
                if (il == rl) v = 0.f;  // self-edge: zero M2 row (agg); diff=0 kills x_upd
                aggP[nt] += v;
                short hh, ll2;
                bf16_split(v, hh, ll2);
                u.sM2[il * 76 + col] =
                    (unsigned int)(unsigned short)hh | ((unsigned int)(unsigned short)ll2 << 16);
            }
        }

        // ---- phase C: Ppre = M2 @ Wx1; phi = silu(P)@wx2; accumulate x_upd ----
        // (wave-local LDS RAW: compiler inserts lgkmcnt; rows are wave-private)
        short8 a2h[2], a2l[2];
#pragma unroll
        for (int kt = 0; kt < 2; ++kt) {
            const uint4v* p = (const uint4v*)&u.sM2[(16 * wv + m) * 76 + kt * 32 + 8 * q];
            uint4v u0 = p[0], u1 = p[1];
            uint4v th, tl;
            th.x = __builtin_amdgcn_perm(u0.y, u0.x, 0x05040100u);
            th.y = __builtin_amdgcn_perm(u0.w, u0.z, 0x05040100u);
            th.z = __builtin_amdgcn_perm(u1.y, u1.x, 0x05040100u);
            th.w = __builtin_amdgcn_perm(u1.w, u1.z, 0x05040100u);
            tl.x = __builtin_amdgcn_perm(u0.y, u0.x, 0x07060302u);
            tl.y = __builtin_amdgcn_perm(u0.w, u0.z, 0x07060302u);
            tl.z = __builtin_amdgcn_perm(u1.y, u1.x, 0x07060302u);
            tl.w = __builtin_amdgcn_perm(u1.w, u1.z, 0x07060302u);
            a2h[kt] = __builtin_bit_cast(short8, th);
            a2l[kt] = __builtin_bit_cast(short8, tl);
        }
        float phiP[4][2] = {};
#pragma unroll
        for (int nt = 0; nt < 4; ++nt) {
            f32x4 acc = {0.f, 0.f, 0.f, 0.f};
#pragma unroll
            for (int kt = 0; kt < 2; ++kt) {
                acc = __builtin_amdgcn_mfma_f32_16x16x32_bf16(a2h[kt], bW3h[nt][kt], acc, 0, 0, 0);
                acc = __builtin_amdgcn_mfma_f32_16x16x32_bf16(a2l[kt], bW3h[nt][kt], acc, 0, 0, 0);
                acc = __builtin_amdgcn_mfma_f32_16x16x32_bf16(a2h[kt], bW3l[nt][kt], acc, 0, 0, 0);
            }
#pragma unroll
            for (int reg = 0; reg < 4; ++reg) {
                float p = silu_f(acc[reg] + bx1v[nt]);
                phiP[reg][0] += p * w20[nt];
                phiP[reg][1] += p * w21[nt];
            }
        }
#pragma unroll
        for (int sh = 1; sh < 16; sh <<= 1) {
#pragma unroll
            for (int reg = 0; reg < 4; ++reg) {
                phiP[reg][0] += __shfl_xor(phiP[reg][0], sh, 64);
                phiP[reg][1] += __shfl_xor(phiP[reg][1], sh, 64);
            }
        }
        if (m == 0) {
#pragma unroll
            for (int reg = 0; reg < 4; ++reg) {
                int il = 16 * wv + 4 * q + reg;
                sPhi[il][0] = phiP[reg][0];
                sPhi[il][1] = phiP[reg][1];
            }
        }
        if (q == 0) {
            int il = 16 * wv + m;
            float f0 = sPhi[il][0] * ik0;
            float f1 = sPhi[il][1] * ik1;
            accX[0] += f0 * dk[0]; accX[1] += f0 * dk[1]; accX[2] += f0 * dk[2];
            accX[3] += f1 * dk[3]; accX[4] += f1 * dk[4]; accX[5] += f1 * dk[5];
        }
    }

    // ---- final cross-quad / cross-wave reductions ----
#pragma unroll
    for (int nt = 0; nt < 4; ++nt) {
        aggP[nt] += __shfl_xor(aggP[nt], 16, 64);
        aggP[nt] += __shfl_xor(aggP[nt], 32, 64);
    }
    if (q == 0) {
#pragma unroll
        for (int nt = 0; nt < 4; ++nt) sAgg[wv][nt * 16 + m] = aggP[nt];
        int il = 16 * wv + m;
#pragma unroll
        for (int c = 0; c < 6; ++c) sXred[il][c] = accX[c];
    }
    __syncthreads();
    if (tid < 64) {
        float s = 0.f;
#pragma unroll
        for (int w = 0; w < 4; ++w) s += sAgg[w][tid];
        agg[r * HD + tid] = s;
    } else if (tid < 70) {
        int c = tid - 64;
        float s = 0.f;
        for (int i = 0; i < 64; ++i) s += sXred[i][c];
        x_upd[r * 6 + c] = s;
    }
}

// ---------------- K3: node update ----------------
__global__ void k_node_upd(float* __restrict__ h, const float* __restrict__ agg,
                           const float* __restrict__ wh1, const float* __restrict__ bh1,
                           const float* __restrict__ wh2, const float* __restrict__ bh2,
                           float* __restrict__ x_vec, const float* __restrict__ x_upd, int l)
{
    int t = blockIdx.x;
    int j = threadIdx.x;  // 64
    __shared__ float sh[HD], sa[HD], su[HD];
    sh[j] = h[t * HD + j];
    sa[j] = agg[t * HD + j];
    __syncthreads();
    const float* w1 = wh1 + (size_t)l * 128 * HD;
    float acc = bh1[l * HD + j];
#pragma unroll
    for (int i = 0; i < HD; ++i) acc += sh[i] * w1[i * HD + j];
#pragma unroll
    for (int i = 0; i < HD; ++i) acc += sa[i] * w1[(HD + i) * HD + j];
    su[j] = silu_f(acc);
    __syncthreads();
    const float* w2 = wh2 + (size_t)l * HD * HD;
    float v = 0.f;
#pragma unroll
    for (int i = 0; i < HD; ++i) v += su[i] * w2[i * HD + j];
    h[t * HD + j] = sh[j] + v + bh2[l * HD + j];
    if (j < 6) x_vec[t * 6 + j] += x_upd[t * 6 + j] * (1.0f / 767.0f);
}

// ---------------- K4: outputs ----------------
__global__ void k_head(const float* __restrict__ h, const float* __restrict__ x_vec,
                       const float* __restrict__ pos, const float* __restrict__ w_head,
                       const float* __restrict__ b_head, float* __restrict__ out)
{
    int t = blockIdx.x;
    int j = threadIdx.x;  // 64
    __shared__ float sh[HD];
    sh[j] = h[t * HD + j];
    __syncthreads();
    float acc = b_head[j];
#pragma unroll
    for (int i = 0; i < HD; ++i) acc += sh[i] * w_head[i * OUTD + j];
    out[TN * 6 + t * OUTD + j] = acc;          // scalars after vectors
    if (j < 6) out[t * 6 + j] = x_vec[t * 6 + j] - pos[t * 3 + (j % 3)];
}

extern "C" void kernel_launch(void* const* d_in, const int* in_sizes, int n_in,
                              void* d_out, int out_size, void* d_ws, size_t ws_size,
                              hipStream_t stream)
{
    const float* pos    = (const float*)d_in[0];
    const float* feat   = (const float*)d_in[1];
    const float* w_emb  = (const float*)d_in[2];
    const float* b_emb  = (const float*)d_in[3];
    const float* we1    = (const float*)d_in[4];
    const float* be1    = (const float*)d_in[5];
    const float* we2    = (const float*)d_in[6];
    const float* be2    = (const float*)d_in[7];
    const float* wx1    = (const float*)d_in[8];
    const float* bx1    = (const float*)d_in[9];
    const float* wx2    = (const float*)d_in[10];
    const float* wh1    = (const float*)d_in[11];
    const float* bh1    = (const float*)d_in[12];
    const float* wh2    = (const float*)d_in[13];
    const float* bh2    = (const float*)d_in[14];
    const float* w_head = (const float*)d_in[15];
    const float* b_head = (const float*)d_in[16];
    float* out = (float*)d_out;

    float* ws    = (float*)d_ws;
    float* h     = ws;                 // TN*HD
    float* x_vec = h + TN * HD;        // TN*6
    float* Abuf  = x_vec + TN * 6;     // TN*HD
    float* Bvbuf = Abuf + TN * HD;     // TN*HD
    float* aggb  = Bvbuf + TN * HD;    // TN*HD
    float* x_upd = aggb + TN * HD;     // TN*6

    k_embed<<<TN, 64, 0, stream>>>(pos, feat, w_emb, b_emb, h, x_vec);
    for (int l = 0; l < LL; ++l) {
        k_node_pre<<<TN, 128, 0, stream>>>(h, we1, be1, l, Abuf, Bvbuf);
        k_edge<<<TN, 256, 0, stream>>>(x_vec, Abuf, Bvbuf, we1, we2, be2,
                                       wx1, bx1, wx2, l, aggb, x_upd);
        k_node_upd<<<TN, 64, 0, stream>>>(h, aggb, wh1, bh1, wh2, bh2, x_vec, x_upd, l);
    }
    k_head<<<TN, 64, 0, stream>>>(h, x_vec, pos, w_head, b_head, out);
}